// Round 14
// baseline (797.590 us; speedup 1.0000x reference)
//
#include <hip/hip_runtime.h>
#include <cstdint>
#include <cstddef>

#define T_LEN 16384
#define BATCH 8
#define NLAYER 9

typedef _Float16 f16;
typedef __attribute__((ext_vector_type(8))) _Float16 f16x8;
typedef __attribute__((ext_vector_type(4))) float f32x4;
#define MFMA_F16 __builtin_amdgcn_mfma_f32_16x16x32_f16

// async global->LDS DMA, 16 B per lane (dst = wave-uniform base + lane*16)
__device__ __forceinline__ void stage16(const f16* g, f16* l) {
    __builtin_amdgcn_global_load_lds(
        (const __attribute__((address_space(1))) unsigned int*)g,
        (__attribute__((address_space(3))) unsigned int*)l, 16, 0, 0);
}

__device__ __forceinline__ float fast_tanh(float x) {
    return 1.0f - 2.0f / (__expf(2.0f * x) + 1.0f);
}

// ---------------------------------------------------------------------------
// Weight prepack to fp16, B-fragment order [n][k32-chunk].  (round-4 layout)
//  wA [12][256][32] pre-swizzled per row (slot i holds logical k-group
//  i ^ ((n>>1)&3)); rows 0-127 = filters, 128-255 = gates.
//  wB [4][256][32] linear (phase 2 reads direct from L2).
// ---------------------------------------------------------------------------
__global__ __launch_bounds__(256) void prep_weights(
    const float* __restrict__ cw, const float* __restrict__ ow,
    const float* __restrict__ o1w, f16* __restrict__ wA, f16* __restrict__ wB)
{
    int n = blockIdx.x * 256 + threadIdx.x;
    const int NA = NLAYER * 12 * 256 * 32;   // 884736
    const int NB = NLAYER * 4 * 256 * 32;    // 294912
    if (n < NA) {
        int kp = n & 31; int q = n >> 5;
        int c = q & 255; q >>= 8;
        int ch = q % 12; int l = q / 12;
        int i = kp >> 3, j = kp & 7;
        int il = i ^ ((c >> 1) & 3);
        int kpl = il * 8 + j;
        int tap = ch >> 2;
        int r = (ch & 3) * 32 + kpl;
        wA[n] = (f16)cw[((size_t)(l * 256 + c) * 128 + r) * 3 + tap];
    } else if (n < NA + NB) {
        int m = n - NA;
        int kp = m & 31; int q = m >> 5;
        int c = q & 255; q >>= 8;
        int ch = q & 3; int l = q >> 2;
        int k = ch * 32 + kp;
        float v = (c < 128) ? ow[(size_t)(l * 128 + c) * 128 + k]
                            : o1w[(size_t)(c - 128) * 1152 + l * 128 + k];
        wB[m] = (f16)v;
    }
}

// h[b][t][r] = tanh(iw[r]*x[b][t] + ib[r]) (fp16);  acc1 zero-init (fp16)
__global__ __launch_bounds__(256) void input_init(
    const float* __restrict__ x, const float* __restrict__ iw,
    const float* __restrict__ ib,
    f16* __restrict__ h, f16* __restrict__ acc1)
{
    int n = blockIdx.x * 256 + threadIdx.x;
    int r = n & 127; int bt = n >> 7;
    h[n] = (f16)fast_tanh(iw[r] * x[bt] + ib[r]);
    acc1[n] = (f16)0.0f;
}

// ---------------------------------------------------------------------------
// One layer, fused. ROUND-13/14: M=128 BLOCK TILE for ARITHMETIC INTENSITY.
// L2-traffic audit (r12 post-mortem): per layer at M=64, wA staging 393 MB +
// wB frags 262 MB + A 196 MB + epilogue ~100 MB ~= 950 MB ~= 27 us floor at
// the 34.5 TB/s L2 ceiling; with MFMA/VALU/HBM floors serializing per era,
// Sigma ~= 72 us ~= the measured 81 invariant. Doubling M halves wA+wB terms
// (blocks 2048->1024): ~650 MB. The per-WAVE program is r9 VERBATIM (passed,
// 749 us) — acc[2][8], in-era read+MFMA, staggered A-prefetch at even eras
// 2..16 into dead regs, value-selects — only indexing widened:
//   512 thr = 8 waves: mg = w>>1 (4x32 = M128), ng = w&1 (N-halves as r9).
//   Staging: 1 stage16/thread/era (512 x 16B = 8 KB half-chunk).
// vmcnt ledger (1-load DMA units, 3-era lead, A-pairs at even eras 2..16;
// event-simulated = r9's exactly halved): prologue 2; e0,1: 2; e2..17: 4;
// e18..20: 2; e21: 1; e22: 0; e23 none.
// LDS: Bsm 32 KB overlaid by zsR+zsS [128][136]x2B x2 = 69632 B ->
// 2 blocks/CU. launch_bounds(512,4) = 128 regs/wave, r9's proven budget.
// DO NOT cap regs below 128: r1's 64-reg cap spilled acc (6x regression).
// ---------------------------------------------------------------------------
__global__ __launch_bounds__(512, 4) void layer_kernel(
    const f16* __restrict__ h_in, f16* __restrict__ h_out,
    f16* __restrict__ acc1,
    const f16* __restrict__ wA,   // [12][256][32] this layer (pre-swizzled)
    const f16* __restrict__ wB,   // [4][256][32]  this layer (linear)
    const float* __restrict__ cb, // conv_b [256]
    const float* __restrict__ ob, // out_b  [128]
    int d)
{
    __shared__ __align__(16) char smem_raw[69632];
    f16* const Bsm = (f16*)smem_raw;            // phase 1: 4 bufs x 4096 f16
    f16* const zsR = (f16*)smem_raw;            // z, then res: [128][136]
    f16* const zsS = (f16*)smem_raw + 17408;    // skip:        [128][136]

    const int tid  = threadIdx.x;
    const int lane = tid & 63;
    const int w    = tid >> 6;      // 0..7
    const int mg   = w >> 1;        // 0..3  (M quarter, 32 rows each)
    const int ng   = w & 1;         // 0..1  (N half, as r9)
    const int col  = lane & 15;
    const int quad = lane >> 4;
    const int b    = blockIdx.y;
    const int bx   = blockIdx.x;    // 0..127
    const int xt   = ((bx & 7) << 4) | (bx >> 3);   // XCD-chunked swizzle
    const int t0   = xt * 128;

    const f16* hb = h_in + (size_t)b * T_LEN * 128;
    const int bswz = (quad ^ ((col >> 1) & 3)) * 8;

    f32x4 acc[2][8];
#pragma unroll
    for (int mt = 0; mt < 2; ++mt)
#pragma unroll
        for (int nt = 0; nt < 8; ++nt) acc[mt][nt] = (f32x4)0.0f;

    f16x8 a[2][4];
    // one k-chunk of A for one tap: 2 loads (uniform count), per-lane select
    auto loadA_cc = [&](int tap, int cc) {
        const int off = (2 - tap) * d;
#pragma unroll
        for (int mt = 0; mt < 2; ++mt) {
            int t = t0 + mg * 32 + mt * 16 + col - off;
            int tc = t < 0 ? 0 : t;
            f16x8 v = *(const f16x8*)&hb[(size_t)tc * 128 + quad * 8 + cc * 32];
            a[mt][cc] = (t >= 0) ? v : (f16x8)(f16)0.0f;
        }
    };

    // ---------------- Phase 1: pre = h * WA, 24 half-chunk eras --------------
    {   // prologue: full tap-0 A (8 loads), DMA half-chunks 0,1,2 (3 loads)
#pragma unroll
        for (int cc = 0; cc < 4; ++cc) loadA_cc(0, cc);
        __builtin_amdgcn_sched_barrier(0);
#pragma unroll
        for (int hh = 0; hh < 3; ++hh)
            stage16(wA + hh * 4096 + tid * 8, Bsm + hh * 4096 + tid * 8);
        __builtin_amdgcn_sched_barrier(0);
        // queue {A x8, D0, D1, D2}: retire A + D0, keep D1,D2
        asm volatile("s_waitcnt vmcnt(2)" ::: "memory");
        __builtin_amdgcn_s_barrier();
        __builtin_amdgcn_sched_barrier(0);
    }

#pragma unroll
    for (int hc = 0; hc < 24; ++hc) {
        // staggered A-prefetch into dead regs (r9 schedule: even eras 2..16)
        if (hc >= 2 && hc <= 16 && (hc & 1) == 0) {
            const int tap = (hc <= 8) ? 1 : 2;
            const int cc  = (hc <= 8) ? ((hc - 2) >> 1) : ((hc - 10) >> 1);
            loadA_cc(tap, cc);
        }
        __builtin_amdgcn_sched_barrier(0);
        if (hc + 3 < 24) {          // issue DMA three eras ahead
            stage16(wA + (hc + 3) * 4096 + tid * 8,
                    Bsm + ((hc + 3) & 3) * 4096 + tid * 8);
        }
        __builtin_amdgcn_sched_barrier(0);
        const f16* bsc = Bsm + (hc & 3) * 4096;
        const int kc    = (hc >> 1) & 3;    // k-chunk within tap
        const int nbase = (hc & 1) * 4;     // even era: filters, odd: gates
#pragma unroll
        for (int ntl = 0; ntl < 4; ++ntl) {
            int row = ng * 64 + ntl * 16 + col;   // local row within 128
            f16x8 bf = *(const f16x8*)&bsc[row * 32 + bswz];
            acc[0][nbase + ntl] = MFMA_F16(a[0][kc], bf, acc[0][nbase + ntl], 0, 0, 0);
            acc[1][nbase + ntl] = MFMA_F16(a[1][kc], bf, acc[1][nbase + ntl], 0, 0, 0);
        }
        __builtin_amdgcn_sched_barrier(0);
        // era-end wait (1-load DMA units; event-simulated ledger)
        if (hc <= 1) {
            asm volatile("s_waitcnt vmcnt(2)" ::: "memory");
        } else if (hc <= 17) {
            asm volatile("s_waitcnt vmcnt(4)" ::: "memory");
        } else if (hc <= 20) {
            asm volatile("s_waitcnt vmcnt(2)" ::: "memory");
        } else if (hc == 21) {
            asm volatile("s_waitcnt vmcnt(1)" ::: "memory");
        } else if (hc == 22) {
            asm volatile("s_waitcnt vmcnt(0)" ::: "memory");
        }
        if (hc < 23) __builtin_amdgcn_s_barrier();
        __builtin_amdgcn_sched_barrier(0);
    }
    __syncthreads();   // all Bsm reads done before z overlays

    // ---- prefetch phase-2 ch0 B-frags (independent of zs; covered by gating)
    f16x8 b0[8];
#pragma unroll
    for (int nt = 0; nt < 8; ++nt) {
        int nb = (nt < 4) ? (ng * 64 + nt * 16)
                          : (128 + ng * 64 + (nt - 4) * 16);
        b0[nt] = *(const f16x8*)&wB[(size_t)(nb + col) * 32 + quad * 8];
    }

    // ---------------- Gating -> zsR (3-trans fused tanh*sigmoid) ------------
#pragma unroll
    for (int nt = 0; nt < 4; ++nt) {
        int j = ng * 64 + nt * 16 + col;
        float cf = cb[j];
        float cg = cb[j + 128];
#pragma unroll
        for (int mt = 0; mt < 2; ++mt)
#pragma unroll
            for (int reg = 0; reg < 4; ++reg) {
                float f = acc[mt][nt][reg]     + cf;
                float g = acc[mt][nt + 4][reg] + cg;
                float E = __builtin_amdgcn_exp2f(2.885390082f * f); // e^(2f)
                float S = __builtin_amdgcn_exp2f(1.442695041f * g); // e^(g)
                float z = (E - 1.0f) * S *
                          __builtin_amdgcn_rcpf((E + 1.0f) * (S + 1.0f));
                zsR[(mg * 32 + mt * 16 + quad * 4 + reg) * 136 + j] = (f16)z;
            }
    }
    __syncthreads();

    // ---------------- Phase 2: [res|skip] = z * WB, K=128 -------------------
#pragma unroll
    for (int mt = 0; mt < 2; ++mt)
#pragma unroll
        for (int nt = 0; nt < 8; ++nt) acc[mt][nt] = (f32x4)0.0f;

#pragma unroll
    for (int ch = 0; ch < 4; ++ch) {
        f16x8 a2[2];
#pragma unroll
        for (int mt = 0; mt < 2; ++mt)
            a2[mt] = *(const f16x8*)&zsR[(mg * 32 + mt * 16 + col) * 136 + ch * 32 + quad * 8];
        const f16* wc = wB + ch * 8192;
#pragma unroll
        for (int nt = 0; nt < 8; ++nt) {
            int nb = (nt < 4) ? (ng * 64 + nt * 16)
                              : (128 + ng * 64 + (nt - 4) * 16);
            f16x8 bf = (ch == 0) ? b0[nt]
                                 : *(const f16x8*)&wc[(nb + col) * 32 + quad * 8];
            acc[0][nt] = MFMA_F16(a2[0], bf, acc[0][nt], 0, 0, 0);
            acc[1][nt] = MFMA_F16(a2[1], bf, acc[1][nt], 0, 0, 0);
        }
    }

    // ---- epilogue global loads issued HERE: covered by 2 barriers + writes
    const int orow = tid >> 2, oseg = tid & 3;   // 128 rows x 4 col-segs
    const size_t gb = (size_t)b * T_LEN * 128 + (size_t)(t0 + orow) * 128 + oseg * 32;
    f16x8 hv[4], av[4];
#pragma unroll
    for (int i = 0; i < 4; ++i) hv[i] = *(const f16x8*)&h_in[gb + i * 8];
#pragma unroll
    for (int i = 0; i < 4; ++i) av[i] = *(const f16x8*)&acc1[gb + i * 8];

    __syncthreads();   // z reads drained before res overwrites zsR

    // ---------------- Merged epilogue: res->zsR, skip->zsS, one barrier -----
#pragma unroll
    for (int nt = 0; nt < 4; ++nt) {
        int n = ng * 64 + nt * 16 + col;
        float o = ob[n];
#pragma unroll
        for (int mt = 0; mt < 2; ++mt)
#pragma unroll
            for (int reg = 0; reg < 4; ++reg) {
                int r = (mg * 32 + mt * 16 + quad * 4 + reg) * 136 + n;
                zsR[r] = (f16)(acc[mt][nt][reg] + o);
                zsS[r] = (f16)acc[mt][nt + 4][reg];
            }
    }
    __syncthreads();
#pragma unroll
    for (int i = 0; i < 4; ++i) {
        f16x8 rv = *(const f16x8*)&zsR[orow * 136 + oseg * 32 + i * 8];
        *(f16x8*)&h_out[gb + i * 8] = hv[i] + rv;
    }
#pragma unroll
    for (int i = 0; i < 4; ++i) {
        f16x8 sv = *(const f16x8*)&zsS[orow * 136 + oseg * 32 + i * 8];
        *(f16x8*)&acc1[gb + i * 8] = av[i] + sv;
    }
}

// out[bt] = o2b + sum_r o2w[r] * tanh(acc1[bt][r] + o1b[r]); one wave per bt
__global__ __launch_bounds__(256) void final_kernel(
    const f16* __restrict__ acc1, const float* __restrict__ b1,
    const float* __restrict__ w2, const float* __restrict__ b2,
    float* __restrict__ out)
{
    int lane = threadIdx.x & 63;
    int w = threadIdx.x >> 6;
    int bt = blockIdx.x * 4 + w;
    float v0 = (float)acc1[(size_t)bt * 128 + lane];
    float v1 = (float)acc1[(size_t)bt * 128 + lane + 64];
    float s = w2[lane] * fast_tanh(v0 + b1[lane]) +
              w2[lane + 64] * fast_tanh(v1 + b1[lane + 64]);
#pragma unroll
    for (int k = 1; k < 64; k <<= 1) s += __shfl_xor(s, k, 64);
    if (lane == 0) out[bt] = s + b2[0];
}

extern "C" void kernel_launch(void* const* d_in, const int* in_sizes, int n_in,
                              void* d_out, int out_size, void* d_ws, size_t ws_size,
                              hipStream_t stream)
{
    const float* x   = (const float*)d_in[0];
    const float* iw  = (const float*)d_in[1];
    const float* ib  = (const float*)d_in[2];
    const float* cw  = (const float*)d_in[3];
    const float* cb  = (const float*)d_in[4];
    const float* ow  = (const float*)d_in[5];
    const float* ob  = (const float*)d_in[6];
    const float* o1w = (const float*)d_in[7];
    const float* o1b = (const float*)d_in[8];
    const float* o2w = (const float*)d_in[9];
    const float* o2b = (const float*)d_in[10];
    float* out = (float*)d_out;

    const size_t HTR = (size_t)BATCH * T_LEN * 128;   // 16777216
    f16* hA   = (f16*)d_ws;
    f16* hB   = hA + HTR;
    f16* acc1 = hB + HTR;
    f16* wAp  = acc1 + HTR;
    f16* wBp  = wAp + (size_t)NLAYER * 12 * 256 * 32;
    // total ~ 3*32 MB + 2.4 MB = ~103 MB of ws

    prep_weights<<<4608, 256, 0, stream>>>(cw, ow, o1w, wAp, wBp);
    input_init<<<65536, 256, 0, stream>>>(x, iw, ib, hA, acc1);

    const int DIL[NLAYER] = {1, 2, 4, 8, 16, 32, 64, 128, 256};
    f16* hin = hA; f16* hout = hB;
    for (int l = 0; l < NLAYER; ++l) {
        layer_kernel<<<dim3(T_LEN / 128, BATCH), 512, 0, stream>>>(
            hin, hout, acc1,
            wAp + (size_t)l * 12 * 256 * 32, wBp + (size_t)l * 4 * 256 * 32,
            cb + l * 256, ob + l * 128, DIL[l]);
        f16* tmp = hin; hin = hout; hout = tmp;
    }
    final_kernel<<<BATCH * T_LEN / 4, 256, 0, stream>>>(acc1, o1b, o2w, o2b, out);
}

// Round 15
// 735.317 us; speedup vs baseline: 1.0847x; 1.0847x over previous
//
#include <hip/hip_runtime.h>
#include <cstdint>
#include <cstddef>

#define T_LEN 16384
#define BATCH 8
#define NLAYER 9

typedef _Float16 f16;
typedef __attribute__((ext_vector_type(8))) _Float16 f16x8;
typedef __attribute__((ext_vector_type(4))) float f32x4;
#define MFMA_F16 __builtin_amdgcn_mfma_f32_16x16x32_f16

// async global->LDS DMA, 16 B per lane (dst = wave-uniform base + lane*16)
__device__ __forceinline__ void stage16(const f16* g, f16* l) {
    __builtin_amdgcn_global_load_lds(
        (const __attribute__((address_space(1))) unsigned int*)g,
        (__attribute__((address_space(3))) unsigned int*)l, 16, 0, 0);
}

__device__ __forceinline__ float fast_tanh(float x) {
    return 1.0f - 2.0f / (__expf(2.0f * x) + 1.0f);
}

// ---------------------------------------------------------------------------
// Weight prepack to fp16, B-fragment order [n][k32-chunk].  (round-4 layout)
//  wA [12][256][32] pre-swizzled per row (slot i holds logical k-group
//  i ^ ((n>>1)&3)); rows 0-127 = filters, 128-255 = gates.
//  wB [4][256][32] linear (phase 2 reads direct from L2).
// ---------------------------------------------------------------------------
__global__ __launch_bounds__(256) void prep_weights(
    const float* __restrict__ cw, const float* __restrict__ ow,
    const float* __restrict__ o1w, f16* __restrict__ wA, f16* __restrict__ wB)
{
    int n = blockIdx.x * 256 + threadIdx.x;
    const int NA = NLAYER * 12 * 256 * 32;   // 884736
    const int NB = NLAYER * 4 * 256 * 32;    // 294912
    if (n < NA) {
        int kp = n & 31; int q = n >> 5;
        int c = q & 255; q >>= 8;
        int ch = q % 12; int l = q / 12;
        int i = kp >> 3, j = kp & 7;
        int il = i ^ ((c >> 1) & 3);
        int kpl = il * 8 + j;
        int tap = ch >> 2;
        int r = (ch & 3) * 32 + kpl;
        wA[n] = (f16)cw[((size_t)(l * 256 + c) * 128 + r) * 3 + tap];
    } else if (n < NA + NB) {
        int m = n - NA;
        int kp = m & 31; int q = m >> 5;
        int c = q & 255; q >>= 8;
        int ch = q & 3; int l = q >> 2;
        int k = ch * 32 + kp;
        float v = (c < 128) ? ow[(size_t)(l * 128 + c) * 128 + k]
                            : o1w[(size_t)(c - 128) * 1152 + l * 128 + k];
        wB[m] = (f16)v;
    }
}

// ---------------------------------------------------------------------------
// input_init, VECTORIZED (round-15): each thread computes 8 consecutive
// channels of one (b,t) and stores one f16x8 (16 B) to h and to acc1.
// The old version stored 2 B/thread across 65536 blocks (Guideline-13
// violation: scalar f16 stores + 8x oversized grid). Grid: 8192 blocks.
// ---------------------------------------------------------------------------
__global__ __launch_bounds__(256) void input_init(
    const float* __restrict__ x, const float* __restrict__ iw,
    const float* __restrict__ ib,
    f16* __restrict__ h, f16* __restrict__ acc1)
{
    int n8 = blockIdx.x * 256 + threadIdx.x;   // 2,097,152 groups of 8
    int bt = n8 >> 4;
    int r0 = (n8 & 15) * 8;
    float xv = x[bt];
    f16x8 hv, zv;
#pragma unroll
    for (int i = 0; i < 8; ++i) {
        hv[i] = (f16)fast_tanh(iw[r0 + i] * xv + ib[r0 + i]);
        zv[i] = (f16)0.0f;
    }
    *(f16x8*)&h[(size_t)bt * 128 + r0]    = hv;
    *(f16x8*)&acc1[(size_t)bt * 128 + r0] = zv;
}

// ---------------------------------------------------------------------------
// One layer, fused — ROUND-9 KERNEL VERBATIM (best measured: 749 us total,
// passed twice). 256 thr = 4 waves (mg = w&1 splits M, ng = w>>1 splits N).
// Block tile M=64 x N=256; wave tile M=32 x N=128. acc[2][8]=64 AGPR + 64
// arch VGPR = 128 -> 4 waves/SIMD.
//
// CLOSED QUESTIONS (do not re-attempt; all measured null or worse):
//  - barrier removal (r5: 16% MfmaUtil unchanged, split was slower)
//  - occupancy up (r8: 6 waves/SIMD = 104 us) or down (r12: 2/SIMD = same)
//  - DMA pipeline depth 1->2->3 (r3/r4/r9: null)
//  - A-prefetch cover 0->6 eras (r9: null)
//  - LDS-read reg double-buffer via (256,3) headroom (r12: null)
//  - L2 traffic halved via M=128 tile (r14: null)
//  - XCD swizzle helps FETCH_SIZE (-25 MB) but not time (kept: free)
// Per-layer invariant 81-86 us across all 16 structures: latency-structure
// bound at ~4x the overlapped resource floor (MFMA 13 / VALU 15 / HBM 17 /
// L2 19 us). The only change that ever moved time: VALU floor cut via
// 3-trans gating (r4, -10 us).
// DO NOT cap regs below 128: r1's 64-reg cap spilled acc (6x regression).
// ---------------------------------------------------------------------------
__global__ __launch_bounds__(256, 4) void layer_kernel(
    const f16* __restrict__ h_in, f16* __restrict__ h_out,
    f16* __restrict__ acc1,
    const f16* __restrict__ wA,   // [12][256][32] this layer (pre-swizzled)
    const f16* __restrict__ wB,   // [4][256][32]  this layer (linear)
    const float* __restrict__ cb, // conv_b [256]
    const float* __restrict__ ob, // out_b  [128]
    int d)
{
    __shared__ __align__(16) char smem_raw[34816];
    f16* const Bsm = (f16*)smem_raw;            // phase 1: 4 bufs x 4096 f16
    f16* const zsR = (f16*)smem_raw;            // z, then res: [64][136]
    f16* const zsS = (f16*)smem_raw + 8704;     // skip:        [64][136]

    const int tid  = threadIdx.x;
    const int lane = tid & 63;
    const int w4   = tid >> 6;
    const int mg   = w4 & 1;
    const int ng   = w4 >> 1;
    const int col  = lane & 15;
    const int quad = lane >> 4;
    const int b    = blockIdx.y;
    const int bx   = blockIdx.x;
    const int xt   = ((bx & 7) << 5) | (bx >> 3);   // XCD-chunked swizzle
    const int t0   = xt * 64;

    const f16* hb = h_in + (size_t)b * T_LEN * 128;
    const int bswz = (quad ^ ((col >> 1) & 3)) * 8;

    f32x4 acc[2][8];
#pragma unroll
    for (int mt = 0; mt < 2; ++mt)
#pragma unroll
        for (int nt = 0; nt < 8; ++nt) acc[mt][nt] = (f32x4)0.0f;

    f16x8 a[2][4];
    // one k-chunk of A for one tap: 2 loads (uniform count), per-lane select
    auto loadA_cc = [&](int tap, int cc) {
        const int off = (2 - tap) * d;
#pragma unroll
        for (int mt = 0; mt < 2; ++mt) {
            int t = t0 + mg * 32 + mt * 16 + col - off;
            int tc = t < 0 ? 0 : t;
            f16x8 v = *(const f16x8*)&hb[(size_t)tc * 128 + quad * 8 + cc * 32];
            a[mt][cc] = (t >= 0) ? v : (f16x8)(f16)0.0f;
        }
    };

    // ---------------- Phase 1: pre = h * WA, 24 half-chunk eras --------------
    {   // prologue: full tap-0 A (8 loads), DMA half-chunks 0,1,2 (6 loads)
#pragma unroll
        for (int cc = 0; cc < 4; ++cc) loadA_cc(0, cc);
        __builtin_amdgcn_sched_barrier(0);
#pragma unroll
        for (int hh = 0; hh < 3; ++hh) {
            const f16* s = wA + hh * 4096 + w4 * 1024 + lane * 8;
            f16* dd = Bsm + hh * 4096 + w4 * 1024;
            stage16(s, dd); stage16(s + 512, dd + 512);
        }
        __builtin_amdgcn_sched_barrier(0);
        // queue {A x8, D0 x2, D1 x2, D2 x2}: retire A + D0, keep D1,D2
        asm volatile("s_waitcnt vmcnt(4)" ::: "memory");
        __builtin_amdgcn_s_barrier();
        __builtin_amdgcn_sched_barrier(0);
    }

#pragma unroll
    for (int hc = 0; hc < 24; ++hc) {
        // staggered A-prefetch into dead regs (tap1 @ e2,4,6,8; tap2 @ e10..16)
        if (hc >= 2 && hc <= 16 && (hc & 1) == 0) {
            const int tap = (hc <= 8) ? 1 : 2;
            const int cc  = (hc <= 8) ? ((hc - 2) >> 1) : ((hc - 10) >> 1);
            loadA_cc(tap, cc);
        }
        __builtin_amdgcn_sched_barrier(0);
        if (hc + 3 < 24) {          // issue DMA three eras ahead
            const f16* s = wA + (hc + 3) * 4096 + w4 * 1024 + lane * 8;
            f16* dd = Bsm + ((hc + 3) & 3) * 4096 + w4 * 1024;
            stage16(s, dd); stage16(s + 512, dd + 512);
        }
        __builtin_amdgcn_sched_barrier(0);
        const f16* bsc = Bsm + (hc & 3) * 4096;
        const int kc    = (hc >> 1) & 3;    // k-chunk within tap
        const int nbase = (hc & 1) * 4;     // even era: filters, odd: gates
#pragma unroll
        for (int ntl = 0; ntl < 4; ++ntl) {
            int row = ng * 64 + ntl * 16 + col;   // local row within 128
            f16x8 bf = *(const f16x8*)&bsc[row * 32 + bswz];
            acc[0][nbase + ntl] = MFMA_F16(a[0][kc], bf, acc[0][nbase + ntl], 0, 0, 0);
            acc[1][nbase + ntl] = MFMA_F16(a[1][kc], bf, acc[1][nbase + ntl], 0, 0, 0);
        }
        __builtin_amdgcn_sched_barrier(0);
        // era-end wait (counts in loads; event-simulated ledger)
        if (hc <= 1) {
            asm volatile("s_waitcnt vmcnt(4)" ::: "memory");
        } else if (hc <= 17) {
            asm volatile("s_waitcnt vmcnt(6)" ::: "memory");
        } else if (hc <= 20) {
            asm volatile("s_waitcnt vmcnt(4)" ::: "memory");
        } else if (hc == 21) {
            asm volatile("s_waitcnt vmcnt(2)" ::: "memory");
        } else if (hc == 22) {
            asm volatile("s_waitcnt vmcnt(0)" ::: "memory");
        }
        if (hc < 23) __builtin_amdgcn_s_barrier();
        __builtin_amdgcn_sched_barrier(0);
    }
    __syncthreads();   // all Bsm reads done before z overlays

    // ---- prefetch phase-2 ch0 B-frags (independent of zs; covered by gating)
    f16x8 b0[8];
#pragma unroll
    for (int nt = 0; nt < 8; ++nt) {
        int nb = (nt < 4) ? (ng * 64 + nt * 16)
                          : (128 + ng * 64 + (nt - 4) * 16);
        b0[nt] = *(const f16x8*)&wB[(size_t)(nb + col) * 32 + quad * 8];
    }

    // ---------------- Gating -> zsR (3-trans fused tanh*sigmoid) ------------
#pragma unroll
    for (int nt = 0; nt < 4; ++nt) {
        int j = ng * 64 + nt * 16 + col;
        float cf = cb[j];
        float cg = cb[j + 128];
#pragma unroll
        for (int mt = 0; mt < 2; ++mt)
#pragma unroll
            for (int reg = 0; reg < 4; ++reg) {
                float f = acc[mt][nt][reg]     + cf;
                float g = acc[mt][nt + 4][reg] + cg;
                float E = __builtin_amdgcn_exp2f(2.885390082f * f); // e^(2f)
                float S = __builtin_amdgcn_exp2f(1.442695041f * g); // e^(g)
                float z = (E - 1.0f) * S *
                          __builtin_amdgcn_rcpf((E + 1.0f) * (S + 1.0f));
                zsR[(mg * 32 + mt * 16 + quad * 4 + reg) * 136 + j] = (f16)z;
            }
    }
    __syncthreads();

    // ---------------- Phase 2: [res|skip] = z * WB, K=128 -------------------
#pragma unroll
    for (int mt = 0; mt < 2; ++mt)
#pragma unroll
        for (int nt = 0; nt < 8; ++nt) acc[mt][nt] = (f32x4)0.0f;

#pragma unroll
    for (int ch = 0; ch < 4; ++ch) {
        f16x8 a2[2];
#pragma unroll
        for (int mt = 0; mt < 2; ++mt)
            a2[mt] = *(const f16x8*)&zsR[(mg * 32 + mt * 16 + col) * 136 + ch * 32 + quad * 8];
        const f16* wc = wB + ch * 8192;
#pragma unroll
        for (int nt = 0; nt < 8; ++nt) {
            int nb = (nt < 4) ? (ng * 64 + nt * 16)
                              : (128 + ng * 64 + (nt - 4) * 16);
            f16x8 bf = (ch == 0) ? b0[nt]
                                 : *(const f16x8*)&wc[(nb + col) * 32 + quad * 8];
            acc[0][nt] = MFMA_F16(a2[0], bf, acc[0][nt], 0, 0, 0);
            acc[1][nt] = MFMA_F16(a2[1], bf, acc[1][nt], 0, 0, 0);
        }
    }

    // ---- epilogue global loads issued HERE: covered by 2 barriers + writes
    const int orow = tid >> 2, oseg = tid & 3;
    const size_t gb = (size_t)b * T_LEN * 128 + (size_t)(t0 + orow) * 128 + oseg * 32;
    f16x8 hv[4], av[4];
#pragma unroll
    for (int i = 0; i < 4; ++i) hv[i] = *(const f16x8*)&h_in[gb + i * 8];
#pragma unroll
    for (int i = 0; i < 4; ++i) av[i] = *(const f16x8*)&acc1[gb + i * 8];

    __syncthreads();   // z reads drained before res overwrites zsR

    // ---------------- Merged epilogue: res->zsR, skip->zsS, one barrier -----
#pragma unroll
    for (int nt = 0; nt < 4; ++nt) {
        int n = ng * 64 + nt * 16 + col;
        float o = ob[n];
#pragma unroll
        for (int mt = 0; mt < 2; ++mt)
#pragma unroll
            for (int reg = 0; reg < 4; ++reg) {
                int r = (mg * 32 + mt * 16 + quad * 4 + reg) * 136 + n;
                zsR[r] = (f16)(acc[mt][nt][reg] + o);
                zsS[r] = (f16)acc[mt][nt + 4][reg];
            }
    }
    __syncthreads();
#pragma unroll
    for (int i = 0; i < 4; ++i) {
        f16x8 rv = *(const f16x8*)&zsR[orow * 136 + oseg * 32 + i * 8];
        *(f16x8*)&h_out[gb + i * 8] = hv[i] + rv;
    }
#pragma unroll
    for (int i = 0; i < 4; ++i) {
        f16x8 sv = *(const f16x8*)&zsS[orow * 136 + oseg * 32 + i * 8];
        *(f16x8*)&acc1[gb + i * 8] = av[i] + sv;
    }
}

// out[bt] = o2b + sum_r o2w[r] * tanh(acc1[bt][r] + o1b[r]); one wave per bt
__global__ __launch_bounds__(256) void final_kernel(
    const f16* __restrict__ acc1, const float* __restrict__ b1,
    const float* __restrict__ w2, const float* __restrict__ b2,
    float* __restrict__ out)
{
    int lane = threadIdx.x & 63;
    int w = threadIdx.x >> 6;
    int bt = blockIdx.x * 4 + w;
    float v0 = (float)acc1[(size_t)bt * 128 + lane];
    float v1 = (float)acc1[(size_t)bt * 128 + lane + 64];
    float s = w2[lane] * fast_tanh(v0 + b1[lane]) +
              w2[lane + 64] * fast_tanh(v1 + b1[lane + 64]);
#pragma unroll
    for (int k = 1; k < 64; k <<= 1) s += __shfl_xor(s, k, 64);
    if (lane == 0) out[bt] = s + b2[0];
}

extern "C" void kernel_launch(void* const* d_in, const int* in_sizes, int n_in,
                              void* d_out, int out_size, void* d_ws, size_t ws_size,
                              hipStream_t stream)
{
    const float* x   = (const float*)d_in[0];
    const float* iw  = (const float*)d_in[1];
    const float* ib  = (const float*)d_in[2];
    const float* cw  = (const float*)d_in[3];
    const float* cb  = (const float*)d_in[4];
    const float* ow  = (const float*)d_in[5];
    const float* ob  = (const float*)d_in[6];
    const float* o1w = (const float*)d_in[7];
    const float* o1b = (const float*)d_in[8];
    const float* o2w = (const float*)d_in[9];
    const float* o2b = (const float*)d_in[10];
    float* out = (float*)d_out;

    const size_t HTR = (size_t)BATCH * T_LEN * 128;   // 16777216
    f16* hA   = (f16*)d_ws;
    f16* hB   = hA + HTR;
    f16* acc1 = hB + HTR;
    f16* wAp  = acc1 + HTR;
    f16* wBp  = wAp + (size_t)NLAYER * 12 * 256 * 32;
    // total ~ 3*32 MB + 2.4 MB = ~103 MB of ws

    prep_weights<<<4608, 256, 0, stream>>>(cw, ow, o1w, wAp, wBp);
    input_init<<<8192, 256, 0, stream>>>(x, iw, ib, hA, acc1);

    const int DIL[NLAYER] = {1, 2, 4, 8, 16, 32, 64, 128, 256};
    f16* hin = hA; f16* hout = hB;
    for (int l = 0; l < NLAYER; ++l) {
        layer_kernel<<<dim3(T_LEN / 64, BATCH), 256, 0, stream>>>(
            hin, hout, acc1,
            wAp + (size_t)l * 12 * 256 * 32, wBp + (size_t)l * 4 * 256 * 32,
            cb + l * 256, ob + l * 128, DIL[l]);
        f16* tmp = hin; hin = hout; hout = tmp;
    }
    final_kernel<<<BATCH * T_LEN / 4, 256, 0, stream>>>(acc1, o1b, o2w, o2b, out);
}

// Round 16
// 729.199 us; speedup vs baseline: 1.0938x; 1.0084x over previous
//
#include <hip/hip_runtime.h>
#include <cstdint>
#include <cstddef>

#define T_LEN 16384
#define BATCH 8
#define NLAYER 9

typedef _Float16 f16;
typedef __attribute__((ext_vector_type(8))) _Float16 f16x8;
typedef __attribute__((ext_vector_type(4))) float f32x4;
#define MFMA_F16 __builtin_amdgcn_mfma_f32_16x16x32_f16

// async global->LDS DMA, 16 B per lane (dst = wave-uniform base + lane*16)
__device__ __forceinline__ void stage16(const f16* g, f16* l) {
    __builtin_amdgcn_global_load_lds(
        (const __attribute__((address_space(1))) unsigned int*)g,
        (__attribute__((address_space(3))) unsigned int*)l, 16, 0, 0);
}

__device__ __forceinline__ float fast_tanh(float x) {
    return 1.0f - 2.0f / (__expf(2.0f * x) + 1.0f);
}

// ---------------------------------------------------------------------------
// Weight prepack to fp16, B-fragment order [n][k32-chunk].  (round-4 layout)
//  wA [12][256][32] pre-swizzled per row (slot i holds logical k-group
//  i ^ ((n>>1)&3)); rows 0-127 = filters, 128-255 = gates.
//  wB [4][256][32] linear; 128 f16 ZEROS appended (zpad: out-of-range
//  A-loads in the layer kernel read this via ADDRESS select — r12-verified).
// ---------------------------------------------------------------------------
__global__ __launch_bounds__(256) void prep_weights(
    const float* __restrict__ cw, const float* __restrict__ ow,
    const float* __restrict__ o1w, f16* __restrict__ wA, f16* __restrict__ wB)
{
    int n = blockIdx.x * 256 + threadIdx.x;
    const int NA = NLAYER * 12 * 256 * 32;   // 884736
    const int NB = NLAYER * 4 * 256 * 32;    // 294912
    if (n < NA) {
        int kp = n & 31; int q = n >> 5;
        int c = q & 255; q >>= 8;
        int ch = q % 12; int l = q / 12;
        int i = kp >> 3, j = kp & 7;
        int il = i ^ ((c >> 1) & 3);
        int kpl = il * 8 + j;
        int tap = ch >> 2;
        int r = (ch & 3) * 32 + kpl;
        wA[n] = (f16)cw[((size_t)(l * 256 + c) * 128 + r) * 3 + tap];
    } else if (n < NA + NB) {
        int m = n - NA;
        int kp = m & 31; int q = m >> 5;
        int c = q & 255; q >>= 8;
        int ch = q & 3; int l = q >> 2;
        int k = ch * 32 + kp;
        float v = (c < 128) ? ow[(size_t)(l * 128 + c) * 128 + k]
                            : o1w[(size_t)(c - 128) * 1152 + l * 128 + k];
        wB[m] = (f16)v;
    } else if (n < NA + NB + 128) {
        wB[n - NA] = (f16)0.0f;    // zpad row (128 f16 of zeros)
    }
}

// ---------------------------------------------------------------------------
// input_init, vectorized (r15): 8 channels/thread, f16x8 stores.
// ---------------------------------------------------------------------------
__global__ __launch_bounds__(256) void input_init(
    const float* __restrict__ x, const float* __restrict__ iw,
    const float* __restrict__ ib,
    f16* __restrict__ h, f16* __restrict__ acc1)
{
    int n8 = blockIdx.x * 256 + threadIdx.x;   // 2,097,152 groups of 8
    int bt = n8 >> 4;
    int r0 = (n8 & 15) * 8;
    float xv = x[bt];
    f16x8 hv, zv;
#pragma unroll
    for (int i = 0; i < 8; ++i) {
        hv[i] = (f16)fast_tanh(iw[r0 + i] * xv + ib[r0 + i]);
        zv[i] = (f16)0.0f;
    }
    *(f16x8*)&h[(size_t)bt * 128 + r0]    = hv;
    *(f16x8*)&acc1[(size_t)bt * 128 + r0] = zv;
}

// ---------------------------------------------------------------------------
// One layer, fused — r9/r15 structure (best: 735 us total) + two VALU
// shaves (the only lever that has EVER moved time in 16 rounds):
//  (a) zpad ADDRESS-select A-loads (r12-verified): 2 addr-cndmask per load
//      instead of 4 value-cndmask; load COUNT unchanged -> ledger unchanged.
//  (b) fma-folded gating: cfs/cgs hoisted per nt; per-z arg = one fmaf.
//
// CLOSED QUESTIONS (measured null or worse; do not re-attempt):
//  barriers (r5) / occupancy both directions (r8,r12) / DMA depth (r3,r4,r9)
//  / A-latency cover (r9) / LDS-read reg pipeline (r12) / L2 traffic halved
//  (r14) / direct-L2 weights (r2) / kernel split (r5) / setprio (r11-12).
//  Per-layer invariant 79.5-86 us across 16 structures, all pipes <20%:
//  latency-structure-bound at ~4x the overlapped resource floor
//  (MFMA 13 / VALU 15 / HBM 17 / L2 19 us).
// DO NOT cap regs below 128: r1's 64-reg cap spilled acc (6x regression).
// ---------------------------------------------------------------------------
__global__ __launch_bounds__(256, 4) void layer_kernel(
    const f16* __restrict__ h_in, f16* __restrict__ h_out,
    f16* __restrict__ acc1,
    const f16* __restrict__ wA,   // [12][256][32] this layer (pre-swizzled)
    const f16* __restrict__ wB,   // [4][256][32]  this layer (linear)
    const f16* __restrict__ zpad, // 128 f16 zeros
    const float* __restrict__ cb, // conv_b [256]
    const float* __restrict__ ob, // out_b  [128]
    int d)
{
    __shared__ __align__(16) char smem_raw[34816];
    f16* const Bsm = (f16*)smem_raw;            // phase 1: 4 bufs x 4096 f16
    f16* const zsR = (f16*)smem_raw;            // z, then res: [64][136]
    f16* const zsS = (f16*)smem_raw + 8704;     // skip:        [64][136]

    const int tid  = threadIdx.x;
    const int lane = tid & 63;
    const int w4   = tid >> 6;
    const int mg   = w4 & 1;
    const int ng   = w4 >> 1;
    const int col  = lane & 15;
    const int quad = lane >> 4;
    const int b    = blockIdx.y;
    const int bx   = blockIdx.x;
    const int xt   = ((bx & 7) << 5) | (bx >> 3);   // XCD-chunked swizzle
    const int t0   = xt * 64;

    const f16* hb = h_in + (size_t)b * T_LEN * 128;
    const int bswz = (quad ^ ((col >> 1) & 3)) * 8;

    f32x4 acc[2][8];
#pragma unroll
    for (int mt = 0; mt < 2; ++mt)
#pragma unroll
        for (int nt = 0; nt < 8; ++nt) acc[mt][nt] = (f32x4)0.0f;

    f16x8 a[2][4];
    // one k-chunk of A for one tap: 2 loads, zpad ADDRESS select (no value
    // selects — address cndmask only; load count identical to r15's ledger)
    auto loadA_cc = [&](int tap, int cc) {
        const int off = (2 - tap) * d;
#pragma unroll
        for (int mt = 0; mt < 2; ++mt) {
            int t = t0 + mg * 32 + mt * 16 + col - off;
            const f16* base = (t >= 0) ? &hb[(size_t)t * 128] : zpad;
            a[mt][cc] = *(const f16x8*)&base[quad * 8 + cc * 32];
        }
    };

    // ---------------- Phase 1: pre = h * WA, 24 half-chunk eras --------------
    {   // prologue: full tap-0 A (8 loads), DMA half-chunks 0,1,2 (6 loads)
#pragma unroll
        for (int cc = 0; cc < 4; ++cc) loadA_cc(0, cc);
        __builtin_amdgcn_sched_barrier(0);
#pragma unroll
        for (int hh = 0; hh < 3; ++hh) {
            const f16* s = wA + hh * 4096 + w4 * 1024 + lane * 8;
            f16* dd = Bsm + hh * 4096 + w4 * 1024;
            stage16(s, dd); stage16(s + 512, dd + 512);
        }
        __builtin_amdgcn_sched_barrier(0);
        // queue {A x8, D0 x2, D1 x2, D2 x2}: retire A + D0, keep D1,D2
        asm volatile("s_waitcnt vmcnt(4)" ::: "memory");
        __builtin_amdgcn_s_barrier();
        __builtin_amdgcn_sched_barrier(0);
    }

#pragma unroll
    for (int hc = 0; hc < 24; ++hc) {
        // staggered A-prefetch into dead regs (tap1 @ e2,4,6,8; tap2 @ e10..16)
        if (hc >= 2 && hc <= 16 && (hc & 1) == 0) {
            const int tap = (hc <= 8) ? 1 : 2;
            const int cc  = (hc <= 8) ? ((hc - 2) >> 1) : ((hc - 10) >> 1);
            loadA_cc(tap, cc);
        }
        __builtin_amdgcn_sched_barrier(0);
        if (hc + 3 < 24) {          // issue DMA three eras ahead
            const f16* s = wA + (hc + 3) * 4096 + w4 * 1024 + lane * 8;
            f16* dd = Bsm + ((hc + 3) & 3) * 4096 + w4 * 1024;
            stage16(s, dd); stage16(s + 512, dd + 512);
        }
        __builtin_amdgcn_sched_barrier(0);
        const f16* bsc = Bsm + (hc & 3) * 4096;
        const int kc    = (hc >> 1) & 3;    // k-chunk within tap
        const int nbase = (hc & 1) * 4;     // even era: filters, odd: gates
#pragma unroll
        for (int ntl = 0; ntl < 4; ++ntl) {
            int row = ng * 64 + ntl * 16 + col;   // local row within 128
            f16x8 bf = *(const f16x8*)&bsc[row * 32 + bswz];
            acc[0][nbase + ntl] = MFMA_F16(a[0][kc], bf, acc[0][nbase + ntl], 0, 0, 0);
            acc[1][nbase + ntl] = MFMA_F16(a[1][kc], bf, acc[1][nbase + ntl], 0, 0, 0);
        }
        __builtin_amdgcn_sched_barrier(0);
        // era-end wait (counts in loads; event-simulated ledger, = r15)
        if (hc <= 1) {
            asm volatile("s_waitcnt vmcnt(4)" ::: "memory");
        } else if (hc <= 17) {
            asm volatile("s_waitcnt vmcnt(6)" ::: "memory");
        } else if (hc <= 20) {
            asm volatile("s_waitcnt vmcnt(4)" ::: "memory");
        } else if (hc == 21) {
            asm volatile("s_waitcnt vmcnt(2)" ::: "memory");
        } else if (hc == 22) {
            asm volatile("s_waitcnt vmcnt(0)" ::: "memory");
        }
        if (hc < 23) __builtin_amdgcn_s_barrier();
        __builtin_amdgcn_sched_barrier(0);
    }
    __syncthreads();   // all Bsm reads done before z overlays

    // ---- prefetch phase-2 ch0 B-frags (independent of zs; covered by gating)
    f16x8 b0[8];
#pragma unroll
    for (int nt = 0; nt < 8; ++nt) {
        int nb = (nt < 4) ? (ng * 64 + nt * 16)
                          : (128 + ng * 64 + (nt - 4) * 16);
        b0[nt] = *(const f16x8*)&wB[(size_t)(nb + col) * 32 + quad * 8];
    }

    // ---------------- Gating -> zsR (3-trans, fma-folded args) --------------
#pragma unroll
    for (int nt = 0; nt < 4; ++nt) {
        int j = ng * 64 + nt * 16 + col;
        float cfs = 2.885390082f * cb[j];         // hoisted: arg = fma(k,acc,c)
        float cgs = 1.442695041f * cb[j + 128];
#pragma unroll
        for (int mt = 0; mt < 2; ++mt)
#pragma unroll
            for (int reg = 0; reg < 4; ++reg) {
                float E = __builtin_amdgcn_exp2f(
                    __builtin_fmaf(2.885390082f, acc[mt][nt][reg], cfs));
                float S = __builtin_amdgcn_exp2f(
                    __builtin_fmaf(1.442695041f, acc[mt][nt + 4][reg], cgs));
                float z = (E - 1.0f) * S *
                          __builtin_amdgcn_rcpf((E + 1.0f) * (S + 1.0f));
                zsR[(mg * 32 + mt * 16 + quad * 4 + reg) * 136 + j] = (f16)z;
            }
    }
    __syncthreads();

    // ---------------- Phase 2: [res|skip] = z * WB, K=128 -------------------
#pragma unroll
    for (int mt = 0; mt < 2; ++mt)
#pragma unroll
        for (int nt = 0; nt < 8; ++nt) acc[mt][nt] = (f32x4)0.0f;

#pragma unroll
    for (int ch = 0; ch < 4; ++ch) {
        f16x8 a2[2];
#pragma unroll
        for (int mt = 0; mt < 2; ++mt)
            a2[mt] = *(const f16x8*)&zsR[(mg * 32 + mt * 16 + col) * 136 + ch * 32 + quad * 8];
        const f16* wc = wB + ch * 8192;
#pragma unroll
        for (int nt = 0; nt < 8; ++nt) {
            int nb = (nt < 4) ? (ng * 64 + nt * 16)
                              : (128 + ng * 64 + (nt - 4) * 16);
            f16x8 bf = (ch == 0) ? b0[nt]
                                 : *(const f16x8*)&wc[(nb + col) * 32 + quad * 8];
            acc[0][nt] = MFMA_F16(a2[0], bf, acc[0][nt], 0, 0, 0);
            acc[1][nt] = MFMA_F16(a2[1], bf, acc[1][nt], 0, 0, 0);
        }
    }

    // ---- epilogue global loads issued HERE: covered by 2 barriers + writes
    const int orow = tid >> 2, oseg = tid & 3;
    const size_t gb = (size_t)b * T_LEN * 128 + (size_t)(t0 + orow) * 128 + oseg * 32;
    f16x8 hv[4], av[4];
#pragma unroll
    for (int i = 0; i < 4; ++i) hv[i] = *(const f16x8*)&h_in[gb + i * 8];
#pragma unroll
    for (int i = 0; i < 4; ++i) av[i] = *(const f16x8*)&acc1[gb + i * 8];

    __syncthreads();   // z reads drained before res overwrites zsR

    // ---------------- Merged epilogue: res->zsR, skip->zsS, one barrier -----
#pragma unroll
    for (int nt = 0; nt < 4; ++nt) {
        int n = ng * 64 + nt * 16 + col;
        float o = ob[n];
#pragma unroll
        for (int mt = 0; mt < 2; ++mt)
#pragma unroll
            for (int reg = 0; reg < 4; ++reg) {
                int r = (mg * 32 + mt * 16 + quad * 4 + reg) * 136 + n;
                zsR[r] = (f16)(acc[mt][nt][reg] + o);
                zsS[r] = (f16)acc[mt][nt + 4][reg];
            }
    }
    __syncthreads();
#pragma unroll
    for (int i = 0; i < 4; ++i) {
        f16x8 rv = *(const f16x8*)&zsR[orow * 136 + oseg * 32 + i * 8];
        *(f16x8*)&h_out[gb + i * 8] = hv[i] + rv;
    }
#pragma unroll
    for (int i = 0; i < 4; ++i) {
        f16x8 sv = *(const f16x8*)&zsS[orow * 136 + oseg * 32 + i * 8];
        *(f16x8*)&acc1[gb + i * 8] = av[i] + sv;
    }
}

// out[bt] = o2b + sum_r o2w[r] * tanh(acc1[bt][r] + o1b[r]); one wave per bt
__global__ __launch_bounds__(256) void final_kernel(
    const f16* __restrict__ acc1, const float* __restrict__ b1,
    const float* __restrict__ w2, const float* __restrict__ b2,
    float* __restrict__ out)
{
    int lane = threadIdx.x & 63;
    int w = threadIdx.x >> 6;
    int bt = blockIdx.x * 4 + w;
    float v0 = (float)acc1[(size_t)bt * 128 + lane];
    float v1 = (float)acc1[(size_t)bt * 128 + lane + 64];
    float s = w2[lane] * fast_tanh(v0 + b1[lane]) +
              w2[lane + 64] * fast_tanh(v1 + b1[lane + 64]);
#pragma unroll
    for (int k = 1; k < 64; k <<= 1) s += __shfl_xor(s, k, 64);
    if (lane == 0) out[bt] = s + b2[0];
}

extern "C" void kernel_launch(void* const* d_in, const int* in_sizes, int n_in,
                              void* d_out, int out_size, void* d_ws, size_t ws_size,
                              hipStream_t stream)
{
    const float* x   = (const float*)d_in[0];
    const float* iw  = (const float*)d_in[1];
    const float* ib  = (const float*)d_in[2];
    const float* cw  = (const float*)d_in[3];
    const float* cb  = (const float*)d_in[4];
    const float* ow  = (const float*)d_in[5];
    const float* ob  = (const float*)d_in[6];
    const float* o1w = (const float*)d_in[7];
    const float* o1b = (const float*)d_in[8];
    const float* o2w = (const float*)d_in[9];
    const float* o2b = (const float*)d_in[10];
    float* out = (float*)d_out;

    const size_t HTR = (size_t)BATCH * T_LEN * 128;   // 16777216
    f16* hA   = (f16*)d_ws;
    f16* hB   = hA + HTR;
    f16* acc1 = hB + HTR;
    f16* wAp  = acc1 + HTR;
    f16* wBp  = wAp + (size_t)NLAYER * 12 * 256 * 32;
    f16* zpad = wBp + (size_t)NLAYER * 4 * 256 * 32;  // 128 f16 zeros
    // total ~ 3*32 MB + 2.4 MB = ~103 MB of ws

    // 4609 blocks: covers NA + NB + 128 (zpad) with the bounds checks
    prep_weights<<<4609, 256, 0, stream>>>(cw, ow, o1w, wAp, wBp);
    input_init<<<8192, 256, 0, stream>>>(x, iw, ib, hA, acc1);

    const int DIL[NLAYER] = {1, 2, 4, 8, 16, 32, 64, 128, 256};
    f16* hin = hA; f16* hout = hB;
    for (int l = 0; l < NLAYER; ++l) {
        layer_kernel<<<dim3(T_LEN / 64, BATCH), 256, 0, stream>>>(
            hin, hout, acc1,
            wAp + (size_t)l * 12 * 256 * 32, wBp + (size_t)l * 4 * 256 * 32,
            zpad, cb + l * 256, ob + l * 128, DIL[l]);
        f16* tmp = hin; hin = hout; hout = tmp;
    }
    final_kernel<<<BATCH * T_LEN / 4, 256, 0, stream>>>(acc1, o1b, o2w, o2b, out);
}